// Round 5
// baseline (1066.548 us; speedup 1.0000x reference)
//
#include <hip/hip_runtime.h>
#include <hip/hip_bf16.h>
#include <stdint.h>

#define N_NODES 100000
#define N_EDGES 1600000
#define HID 128
#define OUT_DIM 64
#define N_LAYERS 3

typedef __attribute__((ext_vector_type(8))) short short8;
typedef __attribute__((ext_vector_type(4))) float v4f;
typedef __attribute__((ext_vector_type(4))) unsigned short ushort4v;

__device__ __forceinline__ float bf2f(unsigned int lo16) {
    union { unsigned int i; float f; } v; v.i = lo16 << 16; return v.f;
}
__device__ __forceinline__ unsigned short f2bf(float f) {
    union { float f; unsigned int i; } v; v.f = f;
    unsigned int r = v.i + 0x7fffu + ((v.i >> 16) & 1u);  // RNE
    return (unsigned short)(r >> 16);
}

// ---------------- edge dtype detect (int64 vs int32 robustness) -----------
__global__ void detect_kernel(const int* __restrict__ raw, int* __restrict__ flag) {
    int is64 = 1;
    for (int i = 1; i < 128; i += 2)
        if (raw[i] != 0) { is64 = 0; break; }
    *flag = is64;
}

// ---------------- histogram of dst off the raw edge buffer ----------------
// 1 edge/thread: scatter-atomic kernels want max thread count (R3 lesson).
__global__ __launch_bounds__(256) void hist1(const int* __restrict__ raw,
                                             const int* __restrict__ flag,
                                             int* __restrict__ deg) {
    int e = blockIdx.x * blockDim.x + threadIdx.x;
    if (e >= N_EDGES) return;
    int d;
    if (*flag) d = (int)((const long long*)raw)[N_EDGES + e];
    else       d = raw[N_EDGES + e];
    atomicAdd(&deg[d], 1);
}

__global__ void scan1_kernel(const int* __restrict__ deg, int* __restrict__ incl,
                             int* __restrict__ bsums, int n) {
    __shared__ int tmp[1024];
    int tid = threadIdx.x;
    int i = blockIdx.x * 1024 + tid;
    int v = (i < n) ? deg[i] : 0;
    tmp[tid] = v;
    __syncthreads();
    for (int off = 1; off < 1024; off <<= 1) {
        int t = (tid >= off) ? tmp[tid - off] : 0;
        __syncthreads();
        tmp[tid] += t;
        __syncthreads();
    }
    if (i < n) incl[i] = tmp[tid];
    if (tid == 1023) bsums[blockIdx.x] = tmp[1023];
}

__global__ void scan2_kernel(int* __restrict__ bsums, int nb) {
    __shared__ int tmp[128];
    int tid = threadIdx.x;
    int v = (tid < nb) ? bsums[tid] : 0;
    tmp[tid] = v;
    __syncthreads();
    for (int off = 1; off < 128; off <<= 1) {
        int t = (tid >= off) ? tmp[tid - off] : 0;
        __syncthreads();
        tmp[tid] += t;
        __syncthreads();
    }
    if (tid < nb) bsums[tid] = tmp[tid] - v;  // exclusive
}

// row_off + inv_deg + cursor (cursor starts at row_off: fill avoids a second
// random read)
__global__ void scan3_kernel(const int* __restrict__ incl, const int* __restrict__ deg,
                             const int* __restrict__ bsums, int* __restrict__ row_off,
                             int* __restrict__ cursor, float* __restrict__ inv_deg, int n) {
    int i = blockIdx.x * blockDim.x + threadIdx.x;
    if (i < n) {
        int ro = incl[i] - deg[i] + bsums[i >> 10];
        row_off[i] = ro;
        cursor[i] = ro;
        int d = deg[i];
        inv_deg[i] = 1.0f / (float)(d > 0 ? d : 1);
    } else if (i == n) {
        row_off[n] = N_EDGES;
    }
}

// ---------------- bucket fill: 1 edge/thread (max latency chains) ---------
__global__ __launch_bounds__(256) void fill1(const int* __restrict__ raw,
                                             const int* __restrict__ flag,
                                             int* __restrict__ cursor,
                                             int* __restrict__ srcs_sorted) {
    int e = blockIdx.x * blockDim.x + threadIdx.x;
    if (e >= N_EDGES) return;
    int s, d;
    if (*flag) {
        const long long* r = (const long long*)raw;
        s = (int)r[e];
        d = (int)r[N_EDGES + e];
    } else {
        s = raw[e];
        d = raw[N_EDGES + e];
    }
    int p = atomicAdd(&cursor[d], 1);
    srcs_sorted[p] = s;
}

// ---------------- weight prep: fp32 -> bf16 transposed -------------------
__global__ void prep_weights(const float* __restrict__ Wl, const float* __restrict__ Wr,
                             const float* __restrict__ fc_w,
                             unsigned short* __restrict__ WlT, unsigned short* __restrict__ WrT,
                             unsigned short* __restrict__ fcT) {
    int idx = blockIdx.x * blockDim.x + threadIdx.x;
    const int WELEMS = N_LAYERS * HID * HID;
    if (idx < WELEMS) {
        int l = idx / (HID * HID);
        int rem = idx - l * HID * HID;
        int k = rem / HID, nn2 = rem - k * HID;
        WlT[l * HID * HID + nn2 * HID + k] = f2bf(Wl[idx]);
        WrT[l * HID * HID + nn2 * HID + k] = f2bf(Wr[idx]);
    } else {
        int j = idx - WELEMS;
        if (j < N_LAYERS * HID * OUT_DIM) {
            int l = j / (HID * OUT_DIM);
            int rem = j - l * HID * OUT_DIM;
            int k = rem / OUT_DIM, o = rem - k * OUT_DIM;
            fcT[l * OUT_DIM * HID + o * HID + k] = f2bf(fc_w[(l * HID + k) * OUT_DIM + o]);
        }
    }
}

__global__ void convert_x(const float* __restrict__ x, unsigned short* __restrict__ xb) {
    int i = blockIdx.x * blockDim.x + threadIdx.x;
    if (i < N_NODES * HID / 4) {
        float4 v = ((const float4*)x)[i];
        ushort4v o;
        o[0] = f2bf(v.x); o[1] = f2bf(v.y); o[2] = f2bf(v.z); o[3] = f2bf(v.w);
        ((ushort4v*)xb)[i] = o;
    }
}

// ---------------- fused layer: mean-gather (LDS) + MFMA ------------------
// Block = 128 nodes, 256 threads = 4 waves. Phase 1: each wave computes 32
// bf16 mean rows into LDS (row pitch 136 shorts: +8 pad -> free 2-way bank
// aliasing). Invalid tail rows are ZERO-FILLED (never leave stale LDS for
// the MFMA B-frags — R4 NaN bug). Phase 2: H = relu(mean@Wl + h@Wr + b).
__global__ __launch_bounds__(256) void layer_fused(
    const unsigned short* __restrict__ hprev,   // bf16 [node][128]
    const int* __restrict__ srcs, const int* __restrict__ row_off,
    const float* __restrict__ inv_deg,
    const unsigned short* __restrict__ WlT,     // [128 n][128 k]
    const unsigned short* __restrict__ WrT,
    const float* __restrict__ bias,
    unsigned short* __restrict__ Hout, int n) {
    __shared__ unsigned short smean[128][136];
    int tid = threadIdx.x;
    int w = tid >> 6, L = tid & 63;   // 4 waves
    int node0 = blockIdx.x * 128;

    // ---- phase 1: mean rows; wave w covers locals w*32 .. w*32+31 ----
    const uint32_t* h2 = (const uint32_t*)hprev;
    for (int i = 0; i < 32; ++i) {
        int local = w * 32 + i;
        int node = node0 + local;
        if (node >= n) {
            *(uint32_t*)&smean[local][L * 2] = 0;
            continue;
        }
        int beg = row_off[node], end = row_off[node + 1];
        float ax = 0.f, ay = 0.f;
        int t = beg;
        for (; t + 8 <= end; t += 8) {
            int ss[8];
            uint32_t v[8];
#pragma unroll
            for (int u = 0; u < 8; ++u) ss[u] = srcs[t + u];
#pragma unroll
            for (int u = 0; u < 8; ++u) v[u] = h2[(size_t)ss[u] * 64 + L];
#pragma unroll
            for (int u = 0; u < 8; ++u) {
                ax += bf2f(v[u] & 0xffffu);
                ay += bf2f(v[u] >> 16);
            }
        }
        for (; t < end; ++t) {
            uint32_t v0 = h2[(size_t)srcs[t] * 64 + L];
            ax += bf2f(v0 & 0xffffu);
            ay += bf2f(v0 >> 16);
        }
        float id = inv_deg[node];
        ax *= id; ay *= id;
        uint32_t packed = (uint32_t)f2bf(ax) | ((uint32_t)f2bf(ay) << 16);
        *(uint32_t*)&smean[local][L * 2] = packed;
    }
    __syncthreads();

    // ---- phase 2: MFMA; wave w -> (colbase, nodebase) tile ----
    int q = L >> 4, r16 = L & 15;
    int colbase = (w & 1) * 64;
    int nodebase = (w >> 1) * 64;

    v4f acc[4][4];
#pragma unroll
    for (int i = 0; i < 4; ++i)
#pragma unroll
        for (int j = 0; j < 4; ++j)
#pragma unroll
            for (int r = 0; r < 4; ++r) acc[i][j][r] = 0.f;

    int nd[4];
#pragma unroll
    for (int j = 0; j < 4; ++j) {
        int t = node0 + nodebase + j * 16 + r16;
        nd[j] = t < n ? t : n - 1;
    }

    // seg 0: mean @ Wl  (B-frags from LDS)
#pragma unroll
    for (int t = 0; t < 4; ++t) {
        int koff = t * 32 + q * 8;
        short8 afr[4], bfr[4];
#pragma unroll
        for (int i = 0; i < 4; ++i)
            afr[i] = *(const short8*)&WlT[(colbase + i * 16 + r16) * HID + koff];
#pragma unroll
        for (int j = 0; j < 4; ++j)
            bfr[j] = *(const short8*)&smean[nodebase + j * 16 + r16][koff];
#pragma unroll
        for (int i = 0; i < 4; ++i)
#pragma unroll
            for (int j = 0; j < 4; ++j)
                acc[i][j] = __builtin_amdgcn_mfma_f32_16x16x32_bf16(afr[i], bfr[j], acc[i][j], 0, 0, 0);
    }
    // seg 1: h @ Wr  (B-frags from global)
#pragma unroll
    for (int t = 0; t < 4; ++t) {
        int koff = t * 32 + q * 8;
        short8 afr[4], bfr[4];
#pragma unroll
        for (int i = 0; i < 4; ++i)
            afr[i] = *(const short8*)&WrT[(colbase + i * 16 + r16) * HID + koff];
#pragma unroll
        for (int j = 0; j < 4; ++j)
            bfr[j] = *(const short8*)&hprev[(size_t)nd[j] * HID + koff];
#pragma unroll
        for (int i = 0; i < 4; ++i)
#pragma unroll
            for (int j = 0; j < 4; ++j)
                acc[i][j] = __builtin_amdgcn_mfma_f32_16x16x32_bf16(afr[i], bfr[j], acc[i][j], 0, 0, 0);
    }

#pragma unroll
    for (int i = 0; i < 4; ++i) {
        int col = colbase + i * 16 + q * 4;
        float4 bv = *(const float4*)&bias[col];
#pragma unroll
        for (int j = 0; j < 4; ++j) {
            int node = node0 + nodebase + j * 16 + r16;
            if (node < n) {
                float v0 = acc[i][j][0] + bv.x;
                float v1 = acc[i][j][1] + bv.y;
                float v2 = acc[i][j][2] + bv.z;
                float v3 = acc[i][j][3] + bv.w;
                ushort4v o;
                o[0] = f2bf(v0 > 0.f ? v0 : 0.f);
                o[1] = f2bf(v1 > 0.f ? v1 : 0.f);
                o[2] = f2bf(v2 > 0.f ? v2 : 0.f);
                o[3] = f2bf(v3 > 0.f ? v3 : 0.f);
                *(ushort4v*)&Hout[(size_t)node * HID + col] = o;
            }
        }
    }
}

// ---------------- fused final FC: out = [h1 h2 h3] @ fc_w + fc_b ---------
__global__ __launch_bounds__(256) void fc_fused(
    const unsigned short* __restrict__ h0, const unsigned short* __restrict__ h1,
    const unsigned short* __restrict__ h2, const unsigned short* __restrict__ fcT,
    const float* __restrict__ fc_b, float* __restrict__ out, int n) {
    int tid = threadIdx.x;
    int w = tid >> 6, L = tid & 63;
    int q = L >> 4, r16 = L & 15;
    int node0 = blockIdx.x * 128 + w * 32;

    int nd[2], valid[2];
#pragma unroll
    for (int j = 0; j < 2; ++j) {
        int t = node0 + j * 16 + r16;
        valid[j] = t < n;
        nd[j] = valid[j] ? t : n - 1;
    }

    v4f acc[4][2];
#pragma unroll
    for (int i = 0; i < 4; ++i) {
        int col = i * 16 + q * 4;
        float4 bv = *(const float4*)&fc_b[col];
#pragma unroll
        for (int j = 0; j < 2; ++j) {
            acc[i][j][0] = bv.x; acc[i][j][1] = bv.y;
            acc[i][j][2] = bv.z; acc[i][j][3] = bv.w;
        }
    }

    const unsigned short* hs[3] = {h0, h1, h2};
#pragma unroll
    for (int l = 0; l < 3; ++l) {
        const unsigned short* H = hs[l];
        const unsigned short* F = fcT + (size_t)l * OUT_DIM * HID;
#pragma unroll
        for (int t = 0; t < 4; ++t) {
            int koff = t * 32 + q * 8;
            short8 afr[4], bfr[2];
#pragma unroll
            for (int i = 0; i < 4; ++i)
                afr[i] = *(const short8*)&F[(i * 16 + r16) * HID + koff];
#pragma unroll
            for (int j = 0; j < 2; ++j)
                bfr[j] = *(const short8*)&H[(size_t)nd[j] * HID + koff];
#pragma unroll
            for (int i = 0; i < 4; ++i)
#pragma unroll
                for (int j = 0; j < 2; ++j)
                    acc[i][j] = __builtin_amdgcn_mfma_f32_16x16x32_bf16(afr[i], bfr[j], acc[i][j], 0, 0, 0);
        }
    }

#pragma unroll
    for (int i = 0; i < 4; ++i) {
        int col = i * 16 + q * 4;
#pragma unroll
        for (int j = 0; j < 2; ++j) {
            if (valid[j])
                *(v4f*)&out[(size_t)nd[j] * OUT_DIM + col] = acc[i][j];
        }
    }
}

extern "C" void kernel_launch(void* const* d_in, const int* in_sizes, int n_in,
                              void* d_out, int out_size, void* d_ws, size_t ws_size,
                              hipStream_t stream) {
    const float* x     = (const float*)d_in[0];
    const int*   edges = (const int*)d_in[1];
    const float* Wl    = (const float*)d_in[2];
    const float* Wr    = (const float*)d_in[3];
    const float* b     = (const float*)d_in[4];
    const float* fc_w  = (const float*)d_in[5];
    const float* fc_b  = (const float*)d_in[6];
    float* out = (float*)d_out;

    char* ws = (char*)d_ws;
    size_t off = 0;
    auto alloc = [&](size_t bytes) {
        void* p = ws + off;
        off = (off + bytes + 255) & ~(size_t)255;
        return p;
    };
    int*   flag        = (int*)alloc(256);
    int*   deg         = (int*)alloc((size_t)N_NODES * 4);
    int*   incl        = (int*)alloc((size_t)N_NODES * 4);
    int*   bsums       = (int*)alloc(128 * 4);
    int*   row_off     = (int*)alloc((size_t)(N_NODES + 1) * 4);
    int*   cursor      = (int*)alloc((size_t)N_NODES * 4);
    float* inv_deg     = (float*)alloc((size_t)N_NODES * 4);
    int*   srcs_sorted = (int*)alloc((size_t)N_EDGES * 4);
    unsigned short* xb    = (unsigned short*)alloc((size_t)N_NODES * HID * 2);
    unsigned short* hA    = (unsigned short*)alloc((size_t)N_NODES * HID * 2);
    unsigned short* hB    = (unsigned short*)alloc((size_t)N_NODES * HID * 2);
    unsigned short* hC    = (unsigned short*)alloc((size_t)N_NODES * HID * 2);
    unsigned short* WlT   = (unsigned short*)alloc((size_t)N_LAYERS * HID * HID * 2);
    unsigned short* WrT   = (unsigned short*)alloc((size_t)N_LAYERS * HID * HID * 2);
    unsigned short* fcT   = (unsigned short*)alloc((size_t)N_LAYERS * OUT_DIM * HID * 2);

    hipMemsetAsync(deg, 0, (size_t)N_NODES * 4, stream);

    detect_kernel<<<1, 1, 0, stream>>>(edges, flag);
    hist1<<<(N_EDGES + 255) / 256, 256, 0, stream>>>(edges, flag, deg);
    int nb = (N_NODES + 1023) / 1024;
    scan1_kernel<<<nb, 1024, 0, stream>>>(deg, incl, bsums, N_NODES);
    scan2_kernel<<<1, 128, 0, stream>>>(bsums, nb);
    scan3_kernel<<<(N_NODES + 1 + 255) / 256, 256, 0, stream>>>(incl, deg, bsums, row_off, cursor, inv_deg, N_NODES);
    fill1<<<(N_EDGES + 255) / 256, 256, 0, stream>>>(edges, flag, cursor, srcs_sorted);

    prep_weights<<<(N_LAYERS * HID * HID + N_LAYERS * HID * OUT_DIM + 255) / 256, 256, 0, stream>>>(
        Wl, Wr, fc_w, WlT, WrT, fcT);
    convert_x<<<(N_NODES * HID / 4 + 255) / 256, 256, 0, stream>>>(x, xb);

    unsigned short* hbufs[3] = {hA, hB, hC};
    const unsigned short* hprev = xb;
    int ngrid = (N_NODES + 127) / 128;
    for (int l = 0; l < N_LAYERS; ++l) {
        layer_fused<<<ngrid, 256, 0, stream>>>(
            hprev, srcs_sorted, row_off, inv_deg,
            WlT + (size_t)l * HID * HID, WrT + (size_t)l * HID * HID,
            b + (size_t)l * HID, hbufs[l], N_NODES);
        hprev = hbufs[l];
    }
    fc_fused<<<ngrid, 256, 0, stream>>>(hA, hB, hC, fcT, fc_b, out, N_NODES);
}

// Round 6
// 682.775 us; speedup vs baseline: 1.5621x; 1.5621x over previous
//
#include <hip/hip_runtime.h>
#include <hip/hip_bf16.h>
#include <stdint.h>

#define N_NODES 100000
#define N_EDGES 1600000
#define HID 128
#define OUT_DIM 64
#define N_LAYERS 3

typedef __attribute__((ext_vector_type(8))) short short8;
typedef __attribute__((ext_vector_type(4))) float v4f;
typedef __attribute__((ext_vector_type(4))) unsigned short ushort4v;

__device__ __forceinline__ float bf2f(unsigned int lo16) {
    union { unsigned int i; float f; } v; v.i = lo16 << 16; return v.f;
}
__device__ __forceinline__ unsigned short f2bf(float f) {
    union { float f; unsigned int i; } v; v.f = f;
    unsigned int r = v.i + 0x7fffu + ((v.i >> 16) & 1u);  // RNE
    return (unsigned short)(r >> 16);
}

// ---------------- edge dtype detect (int64 vs int32 robustness) -----------
__global__ void detect_kernel(const int* __restrict__ raw, int* __restrict__ flag) {
    int is64 = 1;
    for (int i = 1; i < 128; i += 2)
        if (raw[i] != 0) { is64 = 0; break; }
    *flag = is64;
}

// ---------------- histogram of dst off the raw edge buffer ----------------
// 1 edge/thread: scatter-atomic kernels want max thread count (R3/R5 lesson).
__global__ __launch_bounds__(256) void hist1(const int* __restrict__ raw,
                                             const int* __restrict__ flag,
                                             int* __restrict__ deg) {
    int e = blockIdx.x * blockDim.x + threadIdx.x;
    if (e >= N_EDGES) return;
    int d;
    if (*flag) d = (int)((const long long*)raw)[N_EDGES + e];
    else       d = raw[N_EDGES + e];
    atomicAdd(&deg[d], 1);
}

__global__ void scan1_kernel(const int* __restrict__ deg, int* __restrict__ incl,
                             int* __restrict__ bsums, int n) {
    __shared__ int tmp[1024];
    int tid = threadIdx.x;
    int i = blockIdx.x * 1024 + tid;
    int v = (i < n) ? deg[i] : 0;
    tmp[tid] = v;
    __syncthreads();
    for (int off = 1; off < 1024; off <<= 1) {
        int t = (tid >= off) ? tmp[tid - off] : 0;
        __syncthreads();
        tmp[tid] += t;
        __syncthreads();
    }
    if (i < n) incl[i] = tmp[tid];
    if (tid == 1023) bsums[blockIdx.x] = tmp[1023];
}

__global__ void scan2_kernel(int* __restrict__ bsums, int nb) {
    __shared__ int tmp[128];
    int tid = threadIdx.x;
    int v = (tid < nb) ? bsums[tid] : 0;
    tmp[tid] = v;
    __syncthreads();
    for (int off = 1; off < 128; off <<= 1) {
        int t = (tid >= off) ? tmp[tid - off] : 0;
        __syncthreads();
        tmp[tid] += t;
        __syncthreads();
    }
    if (tid < nb) bsums[tid] = tmp[tid] - v;  // exclusive
}

// row_off + inv_deg + cursor (cursor starts at row_off: fill avoids a second
// random read)
__global__ void scan3_kernel(const int* __restrict__ incl, const int* __restrict__ deg,
                             const int* __restrict__ bsums, int* __restrict__ row_off,
                             int* __restrict__ cursor, float* __restrict__ inv_deg, int n) {
    int i = blockIdx.x * blockDim.x + threadIdx.x;
    if (i < n) {
        int ro = incl[i] - deg[i] + bsums[i >> 10];
        row_off[i] = ro;
        cursor[i] = ro;
        int d = deg[i];
        inv_deg[i] = 1.0f / (float)(d > 0 ? d : 1);
    } else if (i == n) {
        row_off[n] = N_EDGES;
    }
}

// ---------------- bucket fill: 1 edge/thread (max latency chains) ---------
__global__ __launch_bounds__(256) void fill1(const int* __restrict__ raw,
                                             const int* __restrict__ flag,
                                             int* __restrict__ cursor,
                                             int* __restrict__ srcs_sorted) {
    int e = blockIdx.x * blockDim.x + threadIdx.x;
    if (e >= N_EDGES) return;
    int s, d;
    if (*flag) {
        const long long* r = (const long long*)raw;
        s = (int)r[e];
        d = (int)r[N_EDGES + e];
    } else {
        s = raw[e];
        d = raw[N_EDGES + e];
    }
    int p = atomicAdd(&cursor[d], 1);
    srcs_sorted[p] = s;
}

// ---------------- weight prep: fp32 -> bf16 transposed -------------------
__global__ void prep_weights(const float* __restrict__ Wl, const float* __restrict__ Wr,
                             const float* __restrict__ fc_w,
                             unsigned short* __restrict__ WlT, unsigned short* __restrict__ WrT,
                             unsigned short* __restrict__ fcT) {
    int idx = blockIdx.x * blockDim.x + threadIdx.x;
    const int WELEMS = N_LAYERS * HID * HID;
    if (idx < WELEMS) {
        int l = idx / (HID * HID);
        int rem = idx - l * HID * HID;
        int k = rem / HID, nn2 = rem - k * HID;
        WlT[l * HID * HID + nn2 * HID + k] = f2bf(Wl[idx]);
        WrT[l * HID * HID + nn2 * HID + k] = f2bf(Wr[idx]);
    } else {
        int j = idx - WELEMS;
        if (j < N_LAYERS * HID * OUT_DIM) {
            int l = j / (HID * OUT_DIM);
            int rem = j - l * HID * OUT_DIM;
            int k = rem / OUT_DIM, o = rem - k * OUT_DIM;
            fcT[l * OUT_DIM * HID + o * HID + k] = f2bf(fc_w[(l * HID + k) * OUT_DIM + o]);
        }
    }
}

__global__ void convert_x(const float* __restrict__ x, unsigned short* __restrict__ xb) {
    int i = blockIdx.x * blockDim.x + threadIdx.x;
    if (i < N_NODES * HID / 4) {
        float4 v = ((const float4*)x)[i];
        ushort4v o;
        o[0] = f2bf(v.x); o[1] = f2bf(v.y); o[2] = f2bf(v.z); o[3] = f2bf(v.w);
        ((ushort4v*)xb)[i] = o;
    }
}

// ---------------- mean aggregation: ONE WAVE PER NODE (R2 shape) ----------
// Max wave count = max outstanding gather chains (R3/R5 lesson).
__global__ __launch_bounds__(256) void agg_bf(
    const unsigned short* __restrict__ h, const int* __restrict__ srcs,
    const int* __restrict__ row_off, const float* __restrict__ inv_deg,
    unsigned short* __restrict__ meanb) {
    int node = blockIdx.x * 4 + (threadIdx.x >> 6);
    int lane = threadIdx.x & 63;
    if (node >= N_NODES) return;
    int beg = row_off[node], end = row_off[node + 1];
    const uint32_t* h2 = (const uint32_t*)h;
    float ax = 0.f, ay = 0.f;
    int t = beg;
    for (; t + 8 <= end; t += 8) {
        int ss[8];
        uint32_t v[8];
#pragma unroll
        for (int u = 0; u < 8; ++u) ss[u] = srcs[t + u];
#pragma unroll
        for (int u = 0; u < 8; ++u) v[u] = h2[(size_t)ss[u] * 64 + lane];
#pragma unroll
        for (int u = 0; u < 8; ++u) {
            ax += bf2f(v[u] & 0xffffu);
            ay += bf2f(v[u] >> 16);
        }
    }
    for (; t < end; ++t) {
        uint32_t v0 = h2[(size_t)srcs[t] * 64 + lane];
        ax += bf2f(v0 & 0xffffu);
        ay += bf2f(v0 >> 16);
    }
    float id = inv_deg[node];
    ax *= id; ay *= id;
    uint32_t packed = (uint32_t)f2bf(ax) | ((uint32_t)f2bf(ay) << 16);
    ((uint32_t*)meanb)[(size_t)node * 64 + lane] = packed;
}

// ---------------- layer: H = relu(mean@Wl + h@Wr + b), bf16 MFMA ---------
__global__ __launch_bounds__(256) void layer_mfma(
    const unsigned short* __restrict__ Am,
    const unsigned short* __restrict__ Ah,
    const unsigned short* __restrict__ WlT,
    const unsigned short* __restrict__ WrT,
    const float* __restrict__ bias,
    unsigned short* __restrict__ Hout, int n) {
    int tid = threadIdx.x;
    int w = tid >> 6, L = tid & 63;
    int q = L >> 4, r16 = L & 15;
    int colbase = (w & 1) * 64;
    int nodebase = (w >> 1) * 64;
    int node0 = blockIdx.x * 128;

    v4f acc[4][4];
#pragma unroll
    for (int i = 0; i < 4; ++i)
#pragma unroll
        for (int j = 0; j < 4; ++j)
#pragma unroll
            for (int r = 0; r < 4; ++r) acc[i][j][r] = 0.f;

    int nd[4];
#pragma unroll
    for (int j = 0; j < 4; ++j) {
        int t = node0 + nodebase + j * 16 + r16;
        nd[j] = t < n ? t : n - 1;
    }

#pragma unroll
    for (int seg = 0; seg < 2; ++seg) {
        const unsigned short* A = seg ? Ah : Am;
        const unsigned short* WT = seg ? WrT : WlT;
#pragma unroll
        for (int t = 0; t < 4; ++t) {
            int koff = t * 32 + q * 8;
            short8 afr[4], bfr[4];
#pragma unroll
            for (int i = 0; i < 4; ++i)
                afr[i] = *(const short8*)&WT[(colbase + i * 16 + r16) * HID + koff];
#pragma unroll
            for (int j = 0; j < 4; ++j)
                bfr[j] = *(const short8*)&A[(size_t)nd[j] * HID + koff];
#pragma unroll
            for (int i = 0; i < 4; ++i)
#pragma unroll
                for (int j = 0; j < 4; ++j)
                    acc[i][j] = __builtin_amdgcn_mfma_f32_16x16x32_bf16(afr[i], bfr[j], acc[i][j], 0, 0, 0);
        }
    }

#pragma unroll
    for (int i = 0; i < 4; ++i) {
        int col = colbase + i * 16 + q * 4;
        float4 bv = *(const float4*)&bias[col];
#pragma unroll
        for (int j = 0; j < 4; ++j) {
            int node = node0 + nodebase + j * 16 + r16;
            if (node < n) {
                float v0 = acc[i][j][0] + bv.x;
                float v1 = acc[i][j][1] + bv.y;
                float v2 = acc[i][j][2] + bv.z;
                float v3 = acc[i][j][3] + bv.w;
                ushort4v o;
                o[0] = f2bf(v0 > 0.f ? v0 : 0.f);
                o[1] = f2bf(v1 > 0.f ? v1 : 0.f);
                o[2] = f2bf(v2 > 0.f ? v2 : 0.f);
                o[3] = f2bf(v3 > 0.f ? v3 : 0.f);
                *(ushort4v*)&Hout[(size_t)node * HID + col] = o;
            }
        }
    }
}

// ---------------- fused final FC: out = [h1 h2 h3] @ fc_w + fc_b ---------
__global__ __launch_bounds__(256) void fc_fused(
    const unsigned short* __restrict__ h0, const unsigned short* __restrict__ h1,
    const unsigned short* __restrict__ h2, const unsigned short* __restrict__ fcT,
    const float* __restrict__ fc_b, float* __restrict__ out, int n) {
    int tid = threadIdx.x;
    int w = tid >> 6, L = tid & 63;
    int q = L >> 4, r16 = L & 15;
    int node0 = blockIdx.x * 128 + w * 32;

    int nd[2], valid[2];
#pragma unroll
    for (int j = 0; j < 2; ++j) {
        int t = node0 + j * 16 + r16;
        valid[j] = t < n;
        nd[j] = valid[j] ? t : n - 1;
    }

    v4f acc[4][2];
#pragma unroll
    for (int i = 0; i < 4; ++i) {
        int col = i * 16 + q * 4;
        float4 bv = *(const float4*)&fc_b[col];
#pragma unroll
        for (int j = 0; j < 2; ++j) {
            acc[i][j][0] = bv.x; acc[i][j][1] = bv.y;
            acc[i][j][2] = bv.z; acc[i][j][3] = bv.w;
        }
    }

    const unsigned short* hs[3] = {h0, h1, h2};
#pragma unroll
    for (int l = 0; l < 3; ++l) {
        const unsigned short* H = hs[l];
        const unsigned short* F = fcT + (size_t)l * OUT_DIM * HID;
#pragma unroll
        for (int t = 0; t < 4; ++t) {
            int koff = t * 32 + q * 8;
            short8 afr[4], bfr[2];
#pragma unroll
            for (int i = 0; i < 4; ++i)
                afr[i] = *(const short8*)&F[(i * 16 + r16) * HID + koff];
#pragma unroll
            for (int j = 0; j < 2; ++j)
                bfr[j] = *(const short8*)&H[(size_t)nd[j] * HID + koff];
#pragma unroll
            for (int i = 0; i < 4; ++i)
#pragma unroll
                for (int j = 0; j < 2; ++j)
                    acc[i][j] = __builtin_amdgcn_mfma_f32_16x16x32_bf16(afr[i], bfr[j], acc[i][j], 0, 0, 0);
        }
    }

#pragma unroll
    for (int i = 0; i < 4; ++i) {
        int col = i * 16 + q * 4;
#pragma unroll
        for (int j = 0; j < 2; ++j) {
            if (valid[j])
                *(v4f*)&out[(size_t)nd[j] * OUT_DIM + col] = acc[i][j];
        }
    }
}

extern "C" void kernel_launch(void* const* d_in, const int* in_sizes, int n_in,
                              void* d_out, int out_size, void* d_ws, size_t ws_size,
                              hipStream_t stream) {
    const float* x     = (const float*)d_in[0];
    const int*   edges = (const int*)d_in[1];
    const float* Wl    = (const float*)d_in[2];
    const float* Wr    = (const float*)d_in[3];
    const float* b     = (const float*)d_in[4];
    const float* fc_w  = (const float*)d_in[5];
    const float* fc_b  = (const float*)d_in[6];
    float* out = (float*)d_out;

    char* ws = (char*)d_ws;
    size_t off = 0;
    auto alloc = [&](size_t bytes) {
        void* p = ws + off;
        off = (off + bytes + 255) & ~(size_t)255;
        return p;
    };
    int*   flag        = (int*)alloc(256);
    int*   deg         = (int*)alloc((size_t)N_NODES * 4);
    int*   incl        = (int*)alloc((size_t)N_NODES * 4);
    int*   bsums       = (int*)alloc(128 * 4);
    int*   row_off     = (int*)alloc((size_t)(N_NODES + 1) * 4);
    int*   cursor      = (int*)alloc((size_t)N_NODES * 4);
    float* inv_deg     = (float*)alloc((size_t)N_NODES * 4);
    int*   srcs_sorted = (int*)alloc((size_t)N_EDGES * 4);
    unsigned short* xb    = (unsigned short*)alloc((size_t)N_NODES * HID * 2);
    unsigned short* meanb = (unsigned short*)alloc((size_t)N_NODES * HID * 2);
    unsigned short* hA    = (unsigned short*)alloc((size_t)N_NODES * HID * 2);
    unsigned short* hB    = (unsigned short*)alloc((size_t)N_NODES * HID * 2);
    unsigned short* hC    = (unsigned short*)alloc((size_t)N_NODES * HID * 2);
    unsigned short* WlT   = (unsigned short*)alloc((size_t)N_LAYERS * HID * HID * 2);
    unsigned short* WrT   = (unsigned short*)alloc((size_t)N_LAYERS * HID * HID * 2);
    unsigned short* fcT   = (unsigned short*)alloc((size_t)N_LAYERS * OUT_DIM * HID * 2);

    hipMemsetAsync(deg, 0, (size_t)N_NODES * 4, stream);

    detect_kernel<<<1, 1, 0, stream>>>(edges, flag);
    hist1<<<(N_EDGES + 255) / 256, 256, 0, stream>>>(edges, flag, deg);
    int nb = (N_NODES + 1023) / 1024;
    scan1_kernel<<<nb, 1024, 0, stream>>>(deg, incl, bsums, N_NODES);
    scan2_kernel<<<1, 128, 0, stream>>>(bsums, nb);
    scan3_kernel<<<(N_NODES + 1 + 255) / 256, 256, 0, stream>>>(incl, deg, bsums, row_off, cursor, inv_deg, N_NODES);
    fill1<<<(N_EDGES + 255) / 256, 256, 0, stream>>>(edges, flag, cursor, srcs_sorted);

    prep_weights<<<(N_LAYERS * HID * HID + N_LAYERS * HID * OUT_DIM + 255) / 256, 256, 0, stream>>>(
        Wl, Wr, fc_w, WlT, WrT, fcT);
    convert_x<<<(N_NODES * HID / 4 + 255) / 256, 256, 0, stream>>>(x, xb);

    unsigned short* hbufs[3] = {hA, hB, hC};
    const unsigned short* hprev = xb;
    int ngrid = (N_NODES + 127) / 128;
    for (int l = 0; l < N_LAYERS; ++l) {
        agg_bf<<<(N_NODES + 3) / 4, 256, 0, stream>>>(hprev, srcs_sorted, row_off, inv_deg, meanb);
        layer_mfma<<<ngrid, 256, 0, stream>>>(
            meanb, hprev, WlT + (size_t)l * HID * HID, WrT + (size_t)l * HID * HID,
            b + (size_t)l * HID, hbufs[l], N_NODES);
        hprev = hbufs[l];
    }
    fc_fused<<<ngrid, 256, 0, stream>>>(hA, hB, hC, fcT, fc_b, out, N_NODES);
}

// Round 7
// 608.011 us; speedup vs baseline: 1.7542x; 1.1230x over previous
//
#include <hip/hip_runtime.h>
#include <hip/hip_bf16.h>
#include <stdint.h>

#define N_NODES 100000
#define N_EDGES 1600000
#define HID 128
#define OUT_DIM 64
#define N_LAYERS 3
#define CAP 64        // ELL row capacity (slots per node); deg~Poisson(16)
#define CAP_SHIFT 6
#define NBINS 4       // fill passes; shrinks active scatter window for L2 residency

typedef __attribute__((ext_vector_type(8))) short short8;
typedef __attribute__((ext_vector_type(4))) float v4f;
typedef __attribute__((ext_vector_type(4))) unsigned short ushort4v;

__device__ __forceinline__ float bf2f(unsigned int lo16) {
    union { unsigned int i; float f; } v; v.i = lo16 << 16; return v.f;
}
__device__ __forceinline__ unsigned short f2bf(float f) {
    union { float f; unsigned int i; } v; v.f = f;
    unsigned int r = v.i + 0x7fffu + ((v.i >> 16) & 1u);  // RNE
    return (unsigned short)(r >> 16);
}

// ---------------- edge dtype detect (int64 vs int32 robustness) -----------
__global__ void detect_kernel(const int* __restrict__ raw, int* __restrict__ flag) {
    int is64 = 1;
    for (int i = 1; i < 128; i += 2)
        if (raw[i] != 0) { is64 = 0; break; }
    *flag = is64;
}

// ---------------- cursor init: ELL row base = node*CAP -------------------
__global__ void init_cursor(int* __restrict__ cursor) {
    int i = blockIdx.x * blockDim.x + threadIdx.x;
    if (i < N_NODES) cursor[i] = i << CAP_SHIFT;
}

// ---------------- ELL fill: single atomic pass, dst-range binned ----------
// 1 edge/thread (max latency chains, R3/R5 lesson). Only edges whose dst is
// in [lo,hi) act this pass -> active scatter window ~6.4MB, L2-resident, so
// cachelines absorb all writes before eviction (kills the 16x writeback
// amplification seen in fill1). Clamp guards the (astronomically unlikely)
// deg>CAP case for memory safety.
__global__ __launch_bounds__(256) void fill_ell(const int* __restrict__ raw,
                                                const int* __restrict__ flag,
                                                int* __restrict__ cursor,
                                                int* __restrict__ ell,
                                                int lo, int hi) {
    int e = blockIdx.x * blockDim.x + threadIdx.x;
    if (e >= N_EDGES) return;
    int s, d;
    if (*flag) {
        const long long* r = (const long long*)raw;
        d = (int)r[N_EDGES + e];
        if (d < lo || d >= hi) return;
        s = (int)r[e];
    } else {
        d = raw[N_EDGES + e];
        if (d < lo || d >= hi) return;
        s = raw[e];
    }
    int p = atomicAdd(&cursor[d], 1);
    if (p < ((d + 1) << CAP_SHIFT)) ell[p] = s;
}

// ---------------- finalize: deg + inv_deg from cursor --------------------
__global__ void finalize_deg(const int* __restrict__ cursor, int* __restrict__ deg,
                             float* __restrict__ inv_deg) {
    int i = blockIdx.x * blockDim.x + threadIdx.x;
    if (i < N_NODES) {
        int d = cursor[i] - (i << CAP_SHIFT);
        if (d > CAP) d = CAP;
        deg[i] = d;
        inv_deg[i] = 1.0f / (float)(d > 0 ? d : 1);
    }
}

// ---------------- weight prep: fp32 -> bf16 transposed -------------------
__global__ void prep_weights(const float* __restrict__ Wl, const float* __restrict__ Wr,
                             const float* __restrict__ fc_w,
                             unsigned short* __restrict__ WlT, unsigned short* __restrict__ WrT,
                             unsigned short* __restrict__ fcT) {
    int idx = blockIdx.x * blockDim.x + threadIdx.x;
    const int WELEMS = N_LAYERS * HID * HID;
    if (idx < WELEMS) {
        int l = idx / (HID * HID);
        int rem = idx - l * HID * HID;
        int k = rem / HID, nn2 = rem - k * HID;
        WlT[l * HID * HID + nn2 * HID + k] = f2bf(Wl[idx]);
        WrT[l * HID * HID + nn2 * HID + k] = f2bf(Wr[idx]);
    } else {
        int j = idx - WELEMS;
        if (j < N_LAYERS * HID * OUT_DIM) {
            int l = j / (HID * OUT_DIM);
            int rem = j - l * HID * OUT_DIM;
            int k = rem / OUT_DIM, o = rem - k * OUT_DIM;
            fcT[l * OUT_DIM * HID + o * HID + k] = f2bf(fc_w[(l * HID + k) * OUT_DIM + o]);
        }
    }
}

__global__ void convert_x(const float* __restrict__ x, unsigned short* __restrict__ xb) {
    int i = blockIdx.x * blockDim.x + threadIdx.x;
    if (i < N_NODES * HID / 4) {
        float4 v = ((const float4*)x)[i];
        ushort4v o;
        o[0] = f2bf(v.x); o[1] = f2bf(v.y); o[2] = f2bf(v.z); o[3] = f2bf(v.w);
        ((ushort4v*)xb)[i] = o;
    }
}

// ---------------- mean aggregation: ONE WAVE PER NODE (ELL rows) ----------
__global__ __launch_bounds__(256) void agg_bf(
    const unsigned short* __restrict__ h, const int* __restrict__ ell,
    const int* __restrict__ deg, const float* __restrict__ inv_deg,
    unsigned short* __restrict__ meanb) {
    int node = blockIdx.x * 4 + (threadIdx.x >> 6);
    int lane = threadIdx.x & 63;
    if (node >= N_NODES) return;
    int beg = node << CAP_SHIFT;
    int end = beg + deg[node];
    const uint32_t* h2 = (const uint32_t*)h;
    float ax = 0.f, ay = 0.f;
    int t = beg;
    for (; t + 8 <= end; t += 8) {
        int ss[8];
        uint32_t v[8];
#pragma unroll
        for (int u = 0; u < 8; ++u) ss[u] = ell[t + u];
#pragma unroll
        for (int u = 0; u < 8; ++u) v[u] = h2[(size_t)ss[u] * 64 + lane];
#pragma unroll
        for (int u = 0; u < 8; ++u) {
            ax += bf2f(v[u] & 0xffffu);
            ay += bf2f(v[u] >> 16);
        }
    }
    for (; t < end; ++t) {
        uint32_t v0 = h2[(size_t)ell[t] * 64 + lane];
        ax += bf2f(v0 & 0xffffu);
        ay += bf2f(v0 >> 16);
    }
    float id = inv_deg[node];
    ax *= id; ay *= id;
    uint32_t packed = (uint32_t)f2bf(ax) | ((uint32_t)f2bf(ay) << 16);
    ((uint32_t*)meanb)[(size_t)node * 64 + lane] = packed;
}

// ---------------- layer: H = relu(mean@Wl + h@Wr + b), bf16 MFMA ---------
__global__ __launch_bounds__(256) void layer_mfma(
    const unsigned short* __restrict__ Am,
    const unsigned short* __restrict__ Ah,
    const unsigned short* __restrict__ WlT,
    const unsigned short* __restrict__ WrT,
    const float* __restrict__ bias,
    unsigned short* __restrict__ Hout, int n) {
    int tid = threadIdx.x;
    int w = tid >> 6, L = tid & 63;
    int q = L >> 4, r16 = L & 15;
    int colbase = (w & 1) * 64;
    int nodebase = (w >> 1) * 64;
    int node0 = blockIdx.x * 128;

    v4f acc[4][4];
#pragma unroll
    for (int i = 0; i < 4; ++i)
#pragma unroll
        for (int j = 0; j < 4; ++j)
#pragma unroll
            for (int r = 0; r < 4; ++r) acc[i][j][r] = 0.f;

    int nd[4];
#pragma unroll
    for (int j = 0; j < 4; ++j) {
        int t = node0 + nodebase + j * 16 + r16;
        nd[j] = t < n ? t : n - 1;
    }

#pragma unroll
    for (int seg = 0; seg < 2; ++seg) {
        const unsigned short* A = seg ? Ah : Am;
        const unsigned short* WT = seg ? WrT : WlT;
#pragma unroll
        for (int t = 0; t < 4; ++t) {
            int koff = t * 32 + q * 8;
            short8 afr[4], bfr[4];
#pragma unroll
            for (int i = 0; i < 4; ++i)
                afr[i] = *(const short8*)&WT[(colbase + i * 16 + r16) * HID + koff];
#pragma unroll
            for (int j = 0; j < 4; ++j)
                bfr[j] = *(const short8*)&A[(size_t)nd[j] * HID + koff];
#pragma unroll
            for (int i = 0; i < 4; ++i)
#pragma unroll
                for (int j = 0; j < 4; ++j)
                    acc[i][j] = __builtin_amdgcn_mfma_f32_16x16x32_bf16(afr[i], bfr[j], acc[i][j], 0, 0, 0);
        }
    }

#pragma unroll
    for (int i = 0; i < 4; ++i) {
        int col = colbase + i * 16 + q * 4;
        float4 bv = *(const float4*)&bias[col];
#pragma unroll
        for (int j = 0; j < 4; ++j) {
            int node = node0 + nodebase + j * 16 + r16;
            if (node < n) {
                float v0 = acc[i][j][0] + bv.x;
                float v1 = acc[i][j][1] + bv.y;
                float v2 = acc[i][j][2] + bv.z;
                float v3 = acc[i][j][3] + bv.w;
                ushort4v o;
                o[0] = f2bf(v0 > 0.f ? v0 : 0.f);
                o[1] = f2bf(v1 > 0.f ? v1 : 0.f);
                o[2] = f2bf(v2 > 0.f ? v2 : 0.f);
                o[3] = f2bf(v3 > 0.f ? v3 : 0.f);
                *(ushort4v*)&Hout[(size_t)node * HID + col] = o;
            }
        }
    }
}

// ---------------- fused final FC: out = [h1 h2 h3] @ fc_w + fc_b ---------
__global__ __launch_bounds__(256) void fc_fused(
    const unsigned short* __restrict__ h0, const unsigned short* __restrict__ h1,
    const unsigned short* __restrict__ h2, const unsigned short* __restrict__ fcT,
    const float* __restrict__ fc_b, float* __restrict__ out, int n) {
    int tid = threadIdx.x;
    int w = tid >> 6, L = tid & 63;
    int q = L >> 4, r16 = L & 15;
    int node0 = blockIdx.x * 128 + w * 32;

    int nd[2], valid[2];
#pragma unroll
    for (int j = 0; j < 2; ++j) {
        int t = node0 + j * 16 + r16;
        valid[j] = t < n;
        nd[j] = valid[j] ? t : n - 1;
    }

    v4f acc[4][2];
#pragma unroll
    for (int i = 0; i < 4; ++i) {
        int col = i * 16 + q * 4;
        float4 bv = *(const float4*)&fc_b[col];
#pragma unroll
        for (int j = 0; j < 2; ++j) {
            acc[i][j][0] = bv.x; acc[i][j][1] = bv.y;
            acc[i][j][2] = bv.z; acc[i][j][3] = bv.w;
        }
    }

    const unsigned short* hs[3] = {h0, h1, h2};
#pragma unroll
    for (int l = 0; l < 3; ++l) {
        const unsigned short* H = hs[l];
        const unsigned short* F = fcT + (size_t)l * OUT_DIM * HID;
#pragma unroll
        for (int t = 0; t < 4; ++t) {
            int koff = t * 32 + q * 8;
            short8 afr[4], bfr[2];
#pragma unroll
            for (int i = 0; i < 4; ++i)
                afr[i] = *(const short8*)&F[(i * 16 + r16) * HID + koff];
#pragma unroll
            for (int j = 0; j < 2; ++j)
                bfr[j] = *(const short8*)&H[(size_t)nd[j] * HID + koff];
#pragma unroll
            for (int i = 0; i < 4; ++i)
#pragma unroll
                for (int j = 0; j < 2; ++j)
                    acc[i][j] = __builtin_amdgcn_mfma_f32_16x16x32_bf16(afr[i], bfr[j], acc[i][j], 0, 0, 0);
        }
    }

#pragma unroll
    for (int i = 0; i < 4; ++i) {
        int col = i * 16 + q * 4;
#pragma unroll
        for (int j = 0; j < 2; ++j) {
            if (valid[j])
                *(v4f*)&out[(size_t)nd[j] * OUT_DIM + col] = acc[i][j];
        }
    }
}

extern "C" void kernel_launch(void* const* d_in, const int* in_sizes, int n_in,
                              void* d_out, int out_size, void* d_ws, size_t ws_size,
                              hipStream_t stream) {
    const float* x     = (const float*)d_in[0];
    const int*   edges = (const int*)d_in[1];
    const float* Wl    = (const float*)d_in[2];
    const float* Wr    = (const float*)d_in[3];
    const float* b     = (const float*)d_in[4];
    const float* fc_w  = (const float*)d_in[5];
    const float* fc_b  = (const float*)d_in[6];
    float* out = (float*)d_out;

    char* ws = (char*)d_ws;
    size_t off = 0;
    auto alloc = [&](size_t bytes) {
        void* p = ws + off;
        off = (off + bytes + 255) & ~(size_t)255;
        return p;
    };
    int*   flag    = (int*)alloc(256);
    int*   cursor  = (int*)alloc((size_t)N_NODES * 4);
    int*   deg     = (int*)alloc((size_t)N_NODES * 4);
    float* inv_deg = (float*)alloc((size_t)N_NODES * 4);
    int*   ell     = (int*)alloc((size_t)N_NODES * CAP * 4);
    unsigned short* xb    = (unsigned short*)alloc((size_t)N_NODES * HID * 2);
    unsigned short* meanb = (unsigned short*)alloc((size_t)N_NODES * HID * 2);
    unsigned short* hA    = (unsigned short*)alloc((size_t)N_NODES * HID * 2);
    unsigned short* hB    = (unsigned short*)alloc((size_t)N_NODES * HID * 2);
    unsigned short* hC    = (unsigned short*)alloc((size_t)N_NODES * HID * 2);
    unsigned short* WlT   = (unsigned short*)alloc((size_t)N_LAYERS * HID * HID * 2);
    unsigned short* WrT   = (unsigned short*)alloc((size_t)N_LAYERS * HID * HID * 2);
    unsigned short* fcT   = (unsigned short*)alloc((size_t)N_LAYERS * OUT_DIM * HID * 2);

    detect_kernel<<<1, 1, 0, stream>>>(edges, flag);
    init_cursor<<<(N_NODES + 255) / 256, 256, 0, stream>>>(cursor);
    for (int p = 0; p < NBINS; ++p) {
        int lo = (int)(((long long)N_NODES * p) / NBINS);
        int hi = (int)(((long long)N_NODES * (p + 1)) / NBINS);
        fill_ell<<<(N_EDGES + 255) / 256, 256, 0, stream>>>(edges, flag, cursor, ell, lo, hi);
    }
    finalize_deg<<<(N_NODES + 255) / 256, 256, 0, stream>>>(cursor, deg, inv_deg);

    prep_weights<<<(N_LAYERS * HID * HID + N_LAYERS * HID * OUT_DIM + 255) / 256, 256, 0, stream>>>(
        Wl, Wr, fc_w, WlT, WrT, fcT);
    convert_x<<<(N_NODES * HID / 4 + 255) / 256, 256, 0, stream>>>(x, xb);

    unsigned short* hbufs[3] = {hA, hB, hC};
    const unsigned short* hprev = xb;
    int ngrid = (N_NODES + 127) / 128;
    for (int l = 0; l < N_LAYERS; ++l) {
        agg_bf<<<(N_NODES + 3) / 4, 256, 0, stream>>>(hprev, ell, deg, inv_deg, meanb);
        layer_mfma<<<ngrid, 256, 0, stream>>>(
            meanb, hprev, WlT + (size_t)l * HID * HID, WrT + (size_t)l * HID * HID,
            b + (size_t)l * HID, hbufs[l], N_NODES);
        hprev = hbufs[l];
    }
    fc_fused<<<ngrid, 256, 0, stream>>>(hA, hB, hC, fcT, fc_b, out, N_NODES);
}

// Round 8
// 573.456 us; speedup vs baseline: 1.8599x; 1.0603x over previous
//
#include <hip/hip_runtime.h>
#include <hip/hip_bf16.h>
#include <stdint.h>

#define N_NODES 100000
#define N_EDGES 1600000
#define HID 128
#define OUT_DIM 64
#define N_LAYERS 3
#define CAP 64        // ELL row capacity (slots per node); deg~Poisson(16)
#define CAP_SHIFT 6
#define NBINS 4       // fill passes; shrinks active scatter window for L2 residency

typedef __attribute__((ext_vector_type(8))) short short8;
typedef __attribute__((ext_vector_type(4))) float v4f;
typedef __attribute__((ext_vector_type(4))) unsigned short ushort4v;

__device__ __forceinline__ float bf2f(unsigned int lo16) {
    union { unsigned int i; float f; } v; v.i = lo16 << 16; return v.f;
}
__device__ __forceinline__ unsigned short f2bf(float f) {
    union { float f; unsigned int i; } v; v.f = f;
    unsigned int r = v.i + 0x7fffu + ((v.i >> 16) & 1u);  // RNE
    return (unsigned short)(r >> 16);
}

// ---------------- edge dtype detect (int64 vs int32 robustness) -----------
__global__ void detect_kernel(const int* __restrict__ raw, int* __restrict__ flag) {
    int is64 = 1;
    for (int i = 1; i < 128; i += 2)
        if (raw[i] != 0) { is64 = 0; break; }
    *flag = is64;
}

// ---------------- cursor init: ELL row base = node*CAP -------------------
__global__ void init_cursor(int* __restrict__ cursor) {
    int i = blockIdx.x * blockDim.x + threadIdx.x;
    if (i < N_NODES) cursor[i] = i << CAP_SHIFT;
}

// ---------------- ELL fill: single atomic pass, dst-range binned ----------
__global__ __launch_bounds__(256) void fill_ell(const int* __restrict__ raw,
                                                const int* __restrict__ flag,
                                                int* __restrict__ cursor,
                                                int* __restrict__ ell,
                                                int lo, int hi) {
    int e = blockIdx.x * blockDim.x + threadIdx.x;
    if (e >= N_EDGES) return;
    int s, d;
    if (*flag) {
        const long long* r = (const long long*)raw;
        d = (int)r[N_EDGES + e];
        if (d < lo || d >= hi) return;
        s = (int)r[e];
    } else {
        d = raw[N_EDGES + e];
        if (d < lo || d >= hi) return;
        s = raw[e];
    }
    int p = atomicAdd(&cursor[d], 1);
    if (p < ((d + 1) << CAP_SHIFT)) ell[p] = s;
}

// ---------------- finalize: deg + inv_deg; pad ELL rows to x16 with -------
// sentinel N_NODES (points at a zeroed row in each h buffer) so the agg
// gather loop has NO scalar tail — every batch of 16 loads is parallel.
__global__ void finalize_deg(const int* __restrict__ cursor, int* __restrict__ deg,
                             float* __restrict__ inv_deg, int* __restrict__ ell) {
    int i = blockIdx.x * blockDim.x + threadIdx.x;
    if (i < N_NODES) {
        int d = cursor[i] - (i << CAP_SHIFT);
        if (d > CAP) d = CAP;
        deg[i] = d;
        inv_deg[i] = 1.0f / (float)(d > 0 ? d : 1);
        int r = (d + 15) & ~15;
        int base = i << CAP_SHIFT;
        for (int p = d; p < r; ++p) ell[base + p] = N_NODES;
    }
}

// ---------------- zero the sentinel row (index N_NODES) of h buffers ------
__global__ void zero_pad_rows(unsigned short* b0, unsigned short* b1,
                              unsigned short* b2, unsigned short* b3) {
    int t = threadIdx.x;           // 256 threads: 4 bufs x 64 dwords
    unsigned short* bufs[4] = {b0, b1, b2, b3};
    uint32_t* p = (uint32_t*)bufs[t >> 6];
    p[(size_t)N_NODES * 64 + (t & 63)] = 0;
}

// ---------------- weight prep: fp32 -> bf16 transposed -------------------
__global__ void prep_weights(const float* __restrict__ Wl, const float* __restrict__ Wr,
                             const float* __restrict__ fc_w,
                             unsigned short* __restrict__ WlT, unsigned short* __restrict__ WrT,
                             unsigned short* __restrict__ fcT) {
    int idx = blockIdx.x * blockDim.x + threadIdx.x;
    const int WELEMS = N_LAYERS * HID * HID;
    if (idx < WELEMS) {
        int l = idx / (HID * HID);
        int rem = idx - l * HID * HID;
        int k = rem / HID, nn2 = rem - k * HID;
        WlT[l * HID * HID + nn2 * HID + k] = f2bf(Wl[idx]);
        WrT[l * HID * HID + nn2 * HID + k] = f2bf(Wr[idx]);
    } else {
        int j = idx - WELEMS;
        if (j < N_LAYERS * HID * OUT_DIM) {
            int l = j / (HID * OUT_DIM);
            int rem = j - l * HID * OUT_DIM;
            int k = rem / OUT_DIM, o = rem - k * OUT_DIM;
            fcT[l * OUT_DIM * HID + o * HID + k] = f2bf(fc_w[(l * HID + k) * OUT_DIM + o]);
        }
    }
}

__global__ void convert_x(const float* __restrict__ x, unsigned short* __restrict__ xb) {
    int i = blockIdx.x * blockDim.x + threadIdx.x;
    if (i < N_NODES * HID / 4) {
        float4 v = ((const float4*)x)[i];
        ushort4v o;
        o[0] = f2bf(v.x); o[1] = f2bf(v.y); o[2] = f2bf(v.z); o[3] = f2bf(v.w);
        ((ushort4v*)xb)[i] = o;
    }
}

// ---------------- mean aggregation: ONE WAVE PER NODE, batched-16 ---------
// ELL rows padded with sentinel -> all 16 gathers per batch are parallel;
// no dependent scalar tail (R7 theory: tail serialization was ~half the time).
__global__ __launch_bounds__(256) void agg_bf(
    const unsigned short* __restrict__ h, const int* __restrict__ ell,
    const int* __restrict__ deg, const float* __restrict__ inv_deg,
    unsigned short* __restrict__ meanb) {
    int node = blockIdx.x * 4 + (threadIdx.x >> 6);
    int lane = threadIdx.x & 63;
    if (node >= N_NODES) return;
    int beg = node << CAP_SHIFT;
    int dg = deg[node];
    int nb = (dg + 15) >> 4;
    const uint32_t* h2 = (const uint32_t*)h;
    float ax = 0.f, ay = 0.f;
    for (int bidx = 0; bidx < nb; ++bidx) {
        const int4* ep = (const int4*)&ell[beg + (bidx << 4)];
        int4 e0 = ep[0], e1 = ep[1], e2 = ep[2], e3 = ep[3];
        int ss[16] = {e0.x, e0.y, e0.z, e0.w, e1.x, e1.y, e1.z, e1.w,
                      e2.x, e2.y, e2.z, e2.w, e3.x, e3.y, e3.z, e3.w};
        uint32_t v[16];
#pragma unroll
        for (int u = 0; u < 16; ++u) v[u] = h2[(size_t)ss[u] * 64 + lane];
#pragma unroll
        for (int u = 0; u < 16; ++u) {
            ax += bf2f(v[u] & 0xffffu);
            ay += bf2f(v[u] >> 16);
        }
    }
    float id = inv_deg[node];
    ax *= id; ay *= id;
    uint32_t packed = (uint32_t)f2bf(ax) | ((uint32_t)f2bf(ay) << 16);
    ((uint32_t*)meanb)[(size_t)node * 64 + lane] = packed;
}

// ---------------- layer: H = relu(mean@Wl + h@Wr + b), bf16 MFMA ---------
__global__ __launch_bounds__(256) void layer_mfma(
    const unsigned short* __restrict__ Am,
    const unsigned short* __restrict__ Ah,
    const unsigned short* __restrict__ WlT,
    const unsigned short* __restrict__ WrT,
    const float* __restrict__ bias,
    unsigned short* __restrict__ Hout, int n) {
    int tid = threadIdx.x;
    int w = tid >> 6, L = tid & 63;
    int q = L >> 4, r16 = L & 15;
    int colbase = (w & 1) * 64;
    int nodebase = (w >> 1) * 64;
    int node0 = blockIdx.x * 128;

    v4f acc[4][4];
#pragma unroll
    for (int i = 0; i < 4; ++i)
#pragma unroll
        for (int j = 0; j < 4; ++j)
#pragma unroll
            for (int r = 0; r < 4; ++r) acc[i][j][r] = 0.f;

    int nd[4];
#pragma unroll
    for (int j = 0; j < 4; ++j) {
        int t = node0 + nodebase + j * 16 + r16;
        nd[j] = t < n ? t : n - 1;
    }

#pragma unroll
    for (int seg = 0; seg < 2; ++seg) {
        const unsigned short* A = seg ? Ah : Am;
        const unsigned short* WT = seg ? WrT : WlT;
#pragma unroll
        for (int t = 0; t < 4; ++t) {
            int koff = t * 32 + q * 8;
            short8 afr[4], bfr[4];
#pragma unroll
            for (int i = 0; i < 4; ++i)
                afr[i] = *(const short8*)&WT[(colbase + i * 16 + r16) * HID + koff];
#pragma unroll
            for (int j = 0; j < 4; ++j)
                bfr[j] = *(const short8*)&A[(size_t)nd[j] * HID + koff];
#pragma unroll
            for (int i = 0; i < 4; ++i)
#pragma unroll
                for (int j = 0; j < 4; ++j)
                    acc[i][j] = __builtin_amdgcn_mfma_f32_16x16x32_bf16(afr[i], bfr[j], acc[i][j], 0, 0, 0);
        }
    }

#pragma unroll
    for (int i = 0; i < 4; ++i) {
        int col = colbase + i * 16 + q * 4;
        float4 bv = *(const float4*)&bias[col];
#pragma unroll
        for (int j = 0; j < 4; ++j) {
            int node = node0 + nodebase + j * 16 + r16;
            if (node < n) {
                float v0 = acc[i][j][0] + bv.x;
                float v1 = acc[i][j][1] + bv.y;
                float v2 = acc[i][j][2] + bv.z;
                float v3 = acc[i][j][3] + bv.w;
                ushort4v o;
                o[0] = f2bf(v0 > 0.f ? v0 : 0.f);
                o[1] = f2bf(v1 > 0.f ? v1 : 0.f);
                o[2] = f2bf(v2 > 0.f ? v2 : 0.f);
                o[3] = f2bf(v3 > 0.f ? v3 : 0.f);
                *(ushort4v*)&Hout[(size_t)node * HID + col] = o;
            }
        }
    }
}

// ---------------- fused final FC: out = [h1 h2 h3] @ fc_w + fc_b ---------
__global__ __launch_bounds__(256) void fc_fused(
    const unsigned short* __restrict__ h0, const unsigned short* __restrict__ h1,
    const unsigned short* __restrict__ h2, const unsigned short* __restrict__ fcT,
    const float* __restrict__ fc_b, float* __restrict__ out, int n) {
    int tid = threadIdx.x;
    int w = tid >> 6, L = tid & 63;
    int q = L >> 4, r16 = L & 15;
    int node0 = blockIdx.x * 128 + w * 32;

    int nd[2], valid[2];
#pragma unroll
    for (int j = 0; j < 2; ++j) {
        int t = node0 + j * 16 + r16;
        valid[j] = t < n;
        nd[j] = valid[j] ? t : n - 1;
    }

    v4f acc[4][2];
#pragma unroll
    for (int i = 0; i < 4; ++i) {
        int col = i * 16 + q * 4;
        float4 bv = *(const float4*)&fc_b[col];
#pragma unroll
        for (int j = 0; j < 2; ++j) {
            acc[i][j][0] = bv.x; acc[i][j][1] = bv.y;
            acc[i][j][2] = bv.z; acc[i][j][3] = bv.w;
        }
    }

    const unsigned short* hs[3] = {h0, h1, h2};
#pragma unroll
    for (int l = 0; l < 3; ++l) {
        const unsigned short* H = hs[l];
        const unsigned short* F = fcT + (size_t)l * OUT_DIM * HID;
#pragma unroll
        for (int t = 0; t < 4; ++t) {
            int koff = t * 32 + q * 8;
            short8 afr[4], bfr[2];
#pragma unroll
            for (int i = 0; i < 4; ++i)
                afr[i] = *(const short8*)&F[(i * 16 + r16) * HID + koff];
#pragma unroll
            for (int j = 0; j < 2; ++j)
                bfr[j] = *(const short8*)&H[(size_t)nd[j] * HID + koff];
#pragma unroll
            for (int i = 0; i < 4; ++i)
#pragma unroll
                for (int j = 0; j < 2; ++j)
                    acc[i][j] = __builtin_amdgcn_mfma_f32_16x16x32_bf16(afr[i], bfr[j], acc[i][j], 0, 0, 0);
        }
    }

#pragma unroll
    for (int i = 0; i < 4; ++i) {
        int col = i * 16 + q * 4;
#pragma unroll
        for (int j = 0; j < 2; ++j) {
            if (valid[j])
                *(v4f*)&out[(size_t)nd[j] * OUT_DIM + col] = acc[i][j];
        }
    }
}

extern "C" void kernel_launch(void* const* d_in, const int* in_sizes, int n_in,
                              void* d_out, int out_size, void* d_ws, size_t ws_size,
                              hipStream_t stream) {
    const float* x     = (const float*)d_in[0];
    const int*   edges = (const int*)d_in[1];
    const float* Wl    = (const float*)d_in[2];
    const float* Wr    = (const float*)d_in[3];
    const float* b     = (const float*)d_in[4];
    const float* fc_w  = (const float*)d_in[5];
    const float* fc_b  = (const float*)d_in[6];
    float* out = (float*)d_out;

    char* ws = (char*)d_ws;
    size_t off = 0;
    auto alloc = [&](size_t bytes) {
        void* p = ws + off;
        off = (off + bytes + 255) & ~(size_t)255;
        return p;
    };
    int*   flag    = (int*)alloc(256);
    int*   cursor  = (int*)alloc((size_t)N_NODES * 4);
    int*   deg     = (int*)alloc((size_t)N_NODES * 4);
    float* inv_deg = (float*)alloc((size_t)N_NODES * 4);
    int*   ell     = (int*)alloc((size_t)N_NODES * CAP * 4);
    // +1 row: zeroed sentinel row for padded gathers
    unsigned short* xb    = (unsigned short*)alloc((size_t)(N_NODES + 1) * HID * 2);
    unsigned short* meanb = (unsigned short*)alloc((size_t)N_NODES * HID * 2);
    unsigned short* hA    = (unsigned short*)alloc((size_t)(N_NODES + 1) * HID * 2);
    unsigned short* hB    = (unsigned short*)alloc((size_t)(N_NODES + 1) * HID * 2);
    unsigned short* hC    = (unsigned short*)alloc((size_t)(N_NODES + 1) * HID * 2);
    unsigned short* WlT   = (unsigned short*)alloc((size_t)N_LAYERS * HID * HID * 2);
    unsigned short* WrT   = (unsigned short*)alloc((size_t)N_LAYERS * HID * HID * 2);
    unsigned short* fcT   = (unsigned short*)alloc((size_t)N_LAYERS * OUT_DIM * HID * 2);

    detect_kernel<<<1, 1, 0, stream>>>(edges, flag);
    init_cursor<<<(N_NODES + 255) / 256, 256, 0, stream>>>(cursor);
    for (int p = 0; p < NBINS; ++p) {
        int lo = (int)(((long long)N_NODES * p) / NBINS);
        int hi = (int)(((long long)N_NODES * (p + 1)) / NBINS);
        fill_ell<<<(N_EDGES + 255) / 256, 256, 0, stream>>>(edges, flag, cursor, ell, lo, hi);
    }
    finalize_deg<<<(N_NODES + 255) / 256, 256, 0, stream>>>(cursor, deg, inv_deg, ell);
    zero_pad_rows<<<1, 256, 0, stream>>>(xb, hA, hB, hC);

    prep_weights<<<(N_LAYERS * HID * HID + N_LAYERS * HID * OUT_DIM + 255) / 256, 256, 0, stream>>>(
        Wl, Wr, fc_w, WlT, WrT, fcT);
    convert_x<<<(N_NODES * HID / 4 + 255) / 256, 256, 0, stream>>>(x, xb);

    unsigned short* hbufs[3] = {hA, hB, hC};
    const unsigned short* hprev = xb;
    int ngrid = (N_NODES + 127) / 128;
    for (int l = 0; l < N_LAYERS; ++l) {
        agg_bf<<<(N_NODES + 3) / 4, 256, 0, stream>>>(hprev, ell, deg, inv_deg, meanb);
        layer_mfma<<<ngrid, 256, 0, stream>>>(
            meanb, hprev, WlT + (size_t)l * HID * HID, WrT + (size_t)l * HID * HID,
            b + (size_t)l * HID, hbufs[l], N_NODES);
        hprev = hbufs[l];
    }
    fc_fused<<<ngrid, 256, 0, stream>>>(hA, hB, hC, fcT, fc_b, out, N_NODES);
}

// Round 9
// 561.010 us; speedup vs baseline: 1.9011x; 1.0222x over previous
//
#include <hip/hip_runtime.h>
#include <hip/hip_bf16.h>
#include <stdint.h>

#define N_NODES 100000
#define N_EDGES 1600000
#define HID 128
#define OUT_DIM 64
#define N_LAYERS 3
#define CAP 64        // ELL row capacity (slots per node); deg~Poisson(16)
#define CAP_SHIFT 6
#define NBINS 4       // fill passes; shrinks active scatter window for L2 residency

typedef __attribute__((ext_vector_type(8))) short short8;
typedef __attribute__((ext_vector_type(4))) float v4f;
typedef __attribute__((ext_vector_type(4))) unsigned short ushort4v;

__device__ __forceinline__ float bf2f(unsigned int lo16) {
    union { unsigned int i; float f; } v; v.i = lo16 << 16; return v.f;
}
__device__ __forceinline__ unsigned short f2bf(float f) {
    union { float f; unsigned int i; } v; v.f = f;
    unsigned int r = v.i + 0x7fffu + ((v.i >> 16) & 1u);  // RNE
    return (unsigned short)(r >> 16);
}

// ---------------- edge dtype detect (int64 vs int32 robustness) -----------
__global__ void detect_kernel(const int* __restrict__ raw, int* __restrict__ flag) {
    int is64 = 1;
    for (int i = 1; i < 128; i += 2)
        if (raw[i] != 0) { is64 = 0; break; }
    *flag = is64;
}

// ---------------- cursor init: ELL row base = node*CAP -------------------
__global__ void init_cursor(int* __restrict__ cursor) {
    int i = blockIdx.x * blockDim.x + threadIdx.x;
    if (i < N_NODES) cursor[i] = i << CAP_SHIFT;
}

// ---------------- ELL fill: single atomic pass, dst-range binned ----------
__global__ __launch_bounds__(256) void fill_ell(const int* __restrict__ raw,
                                                const int* __restrict__ flag,
                                                int* __restrict__ cursor,
                                                int* __restrict__ ell,
                                                int lo, int hi) {
    int e = blockIdx.x * blockDim.x + threadIdx.x;
    if (e >= N_EDGES) return;
    int s, d;
    if (*flag) {
        const long long* r = (const long long*)raw;
        d = (int)r[N_EDGES + e];
        if (d < lo || d >= hi) return;
        s = (int)r[e];
    } else {
        d = raw[N_EDGES + e];
        if (d < lo || d >= hi) return;
        s = raw[e];
    }
    int p = atomicAdd(&cursor[d], 1);
    if (p < ((d + 1) << CAP_SHIFT)) ell[p] = s;
}

// ---------------- finalize: deg + inv_deg; pad ELL rows to x8 with --------
// sentinel N_NODES (zeroed row in each h buffer) so the unroll-8 agg loop
// needs no predication or scalar tail.
__global__ void finalize_deg(const int* __restrict__ cursor, int* __restrict__ deg,
                             float* __restrict__ inv_deg, int* __restrict__ ell) {
    int i = blockIdx.x * blockDim.x + threadIdx.x;
    if (i < N_NODES) {
        int d = cursor[i] - (i << CAP_SHIFT);
        if (d > CAP) d = CAP;
        deg[i] = d;
        inv_deg[i] = 1.0f / (float)(d > 0 ? d : 1);
        int r = (d + 7) & ~7;
        int base = i << CAP_SHIFT;
        for (int p = d; p < r; ++p) ell[base + p] = N_NODES;
    }
}

// ---------------- zero the sentinel row (index N_NODES) of h buffers ------
__global__ void zero_pad_rows(unsigned short* b0, unsigned short* b1,
                              unsigned short* b2, unsigned short* b3) {
    int t = threadIdx.x;           // 256 threads: 4 bufs x 64 dwords
    unsigned short* bufs[4] = {b0, b1, b2, b3};
    uint32_t* p = (uint32_t*)bufs[t >> 6];
    p[(size_t)N_NODES * 64 + (t & 63)] = 0;
}

// ---------------- weight prep: fp32 -> bf16 transposed -------------------
__global__ void prep_weights(const float* __restrict__ Wl, const float* __restrict__ Wr,
                             const float* __restrict__ fc_w,
                             unsigned short* __restrict__ WlT, unsigned short* __restrict__ WrT,
                             unsigned short* __restrict__ fcT) {
    int idx = blockIdx.x * blockDim.x + threadIdx.x;
    const int WELEMS = N_LAYERS * HID * HID;
    if (idx < WELEMS) {
        int l = idx / (HID * HID);
        int rem = idx - l * HID * HID;
        int k = rem / HID, nn2 = rem - k * HID;
        WlT[l * HID * HID + nn2 * HID + k] = f2bf(Wl[idx]);
        WrT[l * HID * HID + nn2 * HID + k] = f2bf(Wr[idx]);
    } else {
        int j = idx - WELEMS;
        if (j < N_LAYERS * HID * OUT_DIM) {
            int l = j / (HID * OUT_DIM);
            int rem = j - l * HID * OUT_DIM;
            int k = rem / OUT_DIM, o = rem - k * OUT_DIM;
            fcT[l * OUT_DIM * HID + o * HID + k] = f2bf(fc_w[(l * HID + k) * OUT_DIM + o]);
        }
    }
}

__global__ void convert_x(const float* __restrict__ x, unsigned short* __restrict__ xb) {
    int i = blockIdx.x * blockDim.x + threadIdx.x;
    if (i < N_NODES * HID / 4) {
        float4 v = ((const float4*)x)[i];
        ushort4v o;
        o[0] = f2bf(v.x); o[1] = f2bf(v.y); o[2] = f2bf(v.z); o[3] = f2bf(v.w);
        ((ushort4v*)xb)[i] = o;
    }
}

// ---------------- mean aggregation: 16 nodes/block, 16 lanes/node ---------
// Each 16-lane group owns one node; each lane covers 8 channels (16B).
// One dwordx4 gather instr covers 4 rows (1KB) -> ~35% fewer issue cycles
// per row than the one-row-per-instr R8 shape. No cross-lane reduction:
// accumulation completes within each lane. ELL x8-padded with sentinel.
__global__ __launch_bounds__(256) void agg_bf(
    const unsigned short* __restrict__ h, const int* __restrict__ ell,
    const int* __restrict__ deg, const float* __restrict__ inv_deg,
    unsigned short* __restrict__ meanb) {
    int tid = threadIdx.x;
    int grp = tid >> 4;          // node slot in block (0..15)
    int lane16 = tid & 15;       // channel octet
    int node = blockIdx.x * 16 + grp;
    bool valid = node < N_NODES;
    int nd = valid ? node : 0;
    int dg = valid ? deg[nd] : 0;
    int dgp = (dg + 7) & ~7;
    int base = nd << CAP_SHIFT;
    const uint4* hv = (const uint4*)h;   // row = 16 uint4
    float a[8];
#pragma unroll
    for (int c = 0; c < 8; ++c) a[c] = 0.f;

    for (int t = 0; t < dgp; t += 8) {
        int idx[8];
#pragma unroll
        for (int u = 0; u < 8; ++u) idx[u] = ell[base + t + u];
        uint4 v[8];
#pragma unroll
        for (int u = 0; u < 8; ++u) v[u] = hv[(size_t)idx[u] * 16 + lane16];
#pragma unroll
        for (int u = 0; u < 8; ++u) {
            a[0] += bf2f(v[u].x & 0xffffu); a[1] += bf2f(v[u].x >> 16);
            a[2] += bf2f(v[u].y & 0xffffu); a[3] += bf2f(v[u].y >> 16);
            a[4] += bf2f(v[u].z & 0xffffu); a[5] += bf2f(v[u].z >> 16);
            a[6] += bf2f(v[u].w & 0xffffu); a[7] += bf2f(v[u].w >> 16);
        }
    }
    if (valid) {
        float id = inv_deg[nd];
        uint4 o;
        o.x = (uint32_t)f2bf(a[0] * id) | ((uint32_t)f2bf(a[1] * id) << 16);
        o.y = (uint32_t)f2bf(a[2] * id) | ((uint32_t)f2bf(a[3] * id) << 16);
        o.z = (uint32_t)f2bf(a[4] * id) | ((uint32_t)f2bf(a[5] * id) << 16);
        o.w = (uint32_t)f2bf(a[6] * id) | ((uint32_t)f2bf(a[7] * id) << 16);
        *(uint4*)&meanb[(size_t)node * HID + lane16 * 8] = o;
    }
}

// ---------------- layer: H = relu(mean@Wl + h@Wr + b), bf16 MFMA ---------
__global__ __launch_bounds__(256) void layer_mfma(
    const unsigned short* __restrict__ Am,
    const unsigned short* __restrict__ Ah,
    const unsigned short* __restrict__ WlT,
    const unsigned short* __restrict__ WrT,
    const float* __restrict__ bias,
    unsigned short* __restrict__ Hout, int n) {
    int tid = threadIdx.x;
    int w = tid >> 6, L = tid & 63;
    int q = L >> 4, r16 = L & 15;
    int colbase = (w & 1) * 64;
    int nodebase = (w >> 1) * 64;
    int node0 = blockIdx.x * 128;

    v4f acc[4][4];
#pragma unroll
    for (int i = 0; i < 4; ++i)
#pragma unroll
        for (int j = 0; j < 4; ++j)
#pragma unroll
            for (int r = 0; r < 4; ++r) acc[i][j][r] = 0.f;

    int nd[4];
#pragma unroll
    for (int j = 0; j < 4; ++j) {
        int t = node0 + nodebase + j * 16 + r16;
        nd[j] = t < n ? t : n - 1;
    }

#pragma unroll
    for (int seg = 0; seg < 2; ++seg) {
        const unsigned short* A = seg ? Ah : Am;
        const unsigned short* WT = seg ? WrT : WlT;
#pragma unroll
        for (int t = 0; t < 4; ++t) {
            int koff = t * 32 + q * 8;
            short8 afr[4], bfr[4];
#pragma unroll
            for (int i = 0; i < 4; ++i)
                afr[i] = *(const short8*)&WT[(colbase + i * 16 + r16) * HID + koff];
#pragma unroll
            for (int j = 0; j < 4; ++j)
                bfr[j] = *(const short8*)&A[(size_t)nd[j] * HID + koff];
#pragma unroll
            for (int i = 0; i < 4; ++i)
#pragma unroll
                for (int j = 0; j < 4; ++j)
                    acc[i][j] = __builtin_amdgcn_mfma_f32_16x16x32_bf16(afr[i], bfr[j], acc[i][j], 0, 0, 0);
        }
    }

#pragma unroll
    for (int i = 0; i < 4; ++i) {
        int col = colbase + i * 16 + q * 4;
        float4 bv = *(const float4*)&bias[col];
#pragma unroll
        for (int j = 0; j < 4; ++j) {
            int node = node0 + nodebase + j * 16 + r16;
            if (node < n) {
                float v0 = acc[i][j][0] + bv.x;
                float v1 = acc[i][j][1] + bv.y;
                float v2 = acc[i][j][2] + bv.z;
                float v3 = acc[i][j][3] + bv.w;
                ushort4v o;
                o[0] = f2bf(v0 > 0.f ? v0 : 0.f);
                o[1] = f2bf(v1 > 0.f ? v1 : 0.f);
                o[2] = f2bf(v2 > 0.f ? v2 : 0.f);
                o[3] = f2bf(v3 > 0.f ? v3 : 0.f);
                *(ushort4v*)&Hout[(size_t)node * HID + col] = o;
            }
        }
    }
}

// ---------------- fused final FC: out = [h1 h2 h3] @ fc_w + fc_b ---------
__global__ __launch_bounds__(256) void fc_fused(
    const unsigned short* __restrict__ h0, const unsigned short* __restrict__ h1,
    const unsigned short* __restrict__ h2, const unsigned short* __restrict__ fcT,
    const float* __restrict__ fc_b, float* __restrict__ out, int n) {
    int tid = threadIdx.x;
    int w = tid >> 6, L = tid & 63;
    int q = L >> 4, r16 = L & 15;
    int node0 = blockIdx.x * 128 + w * 32;

    int nd[2], valid[2];
#pragma unroll
    for (int j = 0; j < 2; ++j) {
        int t = node0 + j * 16 + r16;
        valid[j] = t < n;
        nd[j] = valid[j] ? t : n - 1;
    }

    v4f acc[4][2];
#pragma unroll
    for (int i = 0; i < 4; ++i) {
        int col = i * 16 + q * 4;
        float4 bv = *(const float4*)&fc_b[col];
#pragma unroll
        for (int j = 0; j < 2; ++j) {
            acc[i][j][0] = bv.x; acc[i][j][1] = bv.y;
            acc[i][j][2] = bv.z; acc[i][j][3] = bv.w;
        }
    }

    const unsigned short* hs[3] = {h0, h1, h2};
#pragma unroll
    for (int l = 0; l < 3; ++l) {
        const unsigned short* H = hs[l];
        const unsigned short* F = fcT + (size_t)l * OUT_DIM * HID;
#pragma unroll
        for (int t = 0; t < 4; ++t) {
            int koff = t * 32 + q * 8;
            short8 afr[4], bfr[2];
#pragma unroll
            for (int i = 0; i < 4; ++i)
                afr[i] = *(const short8*)&F[(i * 16 + r16) * HID + koff];
#pragma unroll
            for (int j = 0; j < 2; ++j)
                bfr[j] = *(const short8*)&H[(size_t)nd[j] * HID + koff];
#pragma unroll
            for (int i = 0; i < 4; ++i)
#pragma unroll
                for (int j = 0; j < 2; ++j)
                    acc[i][j] = __builtin_amdgcn_mfma_f32_16x16x32_bf16(afr[i], bfr[j], acc[i][j], 0, 0, 0);
        }
    }

#pragma unroll
    for (int i = 0; i < 4; ++i) {
        int col = i * 16 + q * 4;
#pragma unroll
        for (int j = 0; j < 2; ++j) {
            if (valid[j])
                *(v4f*)&out[(size_t)nd[j] * OUT_DIM + col] = acc[i][j];
        }
    }
}

extern "C" void kernel_launch(void* const* d_in, const int* in_sizes, int n_in,
                              void* d_out, int out_size, void* d_ws, size_t ws_size,
                              hipStream_t stream) {
    const float* x     = (const float*)d_in[0];
    const int*   edges = (const int*)d_in[1];
    const float* Wl    = (const float*)d_in[2];
    const float* Wr    = (const float*)d_in[3];
    const float* b     = (const float*)d_in[4];
    const float* fc_w  = (const float*)d_in[5];
    const float* fc_b  = (const float*)d_in[6];
    float* out = (float*)d_out;

    char* ws = (char*)d_ws;
    size_t off = 0;
    auto alloc = [&](size_t bytes) {
        void* p = ws + off;
        off = (off + bytes + 255) & ~(size_t)255;
        return p;
    };
    int*   flag    = (int*)alloc(256);
    int*   cursor  = (int*)alloc((size_t)N_NODES * 4);
    int*   deg     = (int*)alloc((size_t)N_NODES * 4);
    float* inv_deg = (float*)alloc((size_t)N_NODES * 4);
    int*   ell     = (int*)alloc((size_t)N_NODES * CAP * 4);
    // +1 row: zeroed sentinel row for padded gathers
    unsigned short* xb    = (unsigned short*)alloc((size_t)(N_NODES + 1) * HID * 2);
    unsigned short* meanb = (unsigned short*)alloc((size_t)N_NODES * HID * 2);
    unsigned short* hA    = (unsigned short*)alloc((size_t)(N_NODES + 1) * HID * 2);
    unsigned short* hB    = (unsigned short*)alloc((size_t)(N_NODES + 1) * HID * 2);
    unsigned short* hC    = (unsigned short*)alloc((size_t)(N_NODES + 1) * HID * 2);
    unsigned short* WlT   = (unsigned short*)alloc((size_t)N_LAYERS * HID * HID * 2);
    unsigned short* WrT   = (unsigned short*)alloc((size_t)N_LAYERS * HID * HID * 2);
    unsigned short* fcT   = (unsigned short*)alloc((size_t)N_LAYERS * OUT_DIM * HID * 2);

    detect_kernel<<<1, 1, 0, stream>>>(edges, flag);
    init_cursor<<<(N_NODES + 255) / 256, 256, 0, stream>>>(cursor);
    for (int p = 0; p < NBINS; ++p) {
        int lo = (int)(((long long)N_NODES * p) / NBINS);
        int hi = (int)(((long long)N_NODES * (p + 1)) / NBINS);
        fill_ell<<<(N_EDGES + 255) / 256, 256, 0, stream>>>(edges, flag, cursor, ell, lo, hi);
    }
    finalize_deg<<<(N_NODES + 255) / 256, 256, 0, stream>>>(cursor, deg, inv_deg, ell);
    zero_pad_rows<<<1, 256, 0, stream>>>(xb, hA, hB, hC);

    prep_weights<<<(N_LAYERS * HID * HID + N_LAYERS * HID * OUT_DIM + 255) / 256, 256, 0, stream>>>(
        Wl, Wr, fc_w, WlT, WrT, fcT);
    convert_x<<<(N_NODES * HID / 4 + 255) / 256, 256, 0, stream>>>(x, xb);

    unsigned short* hbufs[3] = {hA, hB, hC};
    const unsigned short* hprev = xb;
    int ngrid = (N_NODES + 127) / 128;
    for (int l = 0; l < N_LAYERS; ++l) {
        agg_bf<<<(N_NODES + 15) / 16, 256, 0, stream>>>(hprev, ell, deg, inv_deg, meanb);
        layer_mfma<<<ngrid, 256, 0, stream>>>(
            meanb, hprev, WlT + (size_t)l * HID * HID, WrT + (size_t)l * HID * HID,
            b + (size_t)l * HID, hbufs[l], N_NODES);
        hprev = hbufs[l];
    }
    fc_fused<<<ngrid, 256, 0, stream>>>(hA, hB, hC, fcT, fc_b, out, N_NODES);
}